// Round 9
// baseline (197.118 us; speedup 1.0000x reference)
//
#include <hip/hip_runtime.h>
#include <math.h>

#define KS 11
#define CHUNK 56      // output rows per block; 66 total steps = 3 x 22 (lcm(2,11))
#define GRIDY 10      // 10*56 = 560 >= 512; tail rows masked out of the sum
#define IMW 512
#define IMH 512

struct G11 { float g[KS]; };

typedef int   v4i __attribute__((ext_vector_type(4)));
typedef float f2  __attribute__((ext_vector_type(2)));

// CK-style direct binding to the raw buffer load intrinsic: compiler tracks
// the load (auto waitcnt), folds constant voffset adds into the 12-bit imm.
__device__ float
raw_buf_load_f32(v4i srsrc, int voffset, int soffset, int aux)
    __asm("llvm.amdgcn.raw.buffer.load.f32");

// SRD over ONE image row: num_records = IMW*4 bytes, stride 0.
// OOB lanes (voffset < 0 treated as huge unsigned, or >= IMW*4) return 0 —
// exactly the reference conv's zero-padding, at zero VALU cost.
__device__ inline v4i make_row_srd(const float* row) {
    union { const float* p; unsigned u[2]; } a; a.p = row;
    v4i r;
    r.x = (int)a.u[0];
    r.y = (int)a.u[1];
    r.z = IMW * 4;          // num_records (bytes, stride==0)
    r.w = 0x00020000;       // raw untyped dword access
    return r;
}

// Each thread owns one output column x and streams rows downward.
// {p,t} packed as float2 lanes (twin conv chains -> v_pk_* fp32).
// Software-pipelined: step s issues loads for row s+1 into one named
// prefetch buffer while the h-conv consumes the other (T14 in-register),
// hiding L1/L2 latency inside the wave. Ring slot and buffer parity are
// compile-time constants (22-step unroll = lcm(2,11)).
__global__ __launch_bounds__(256, 4) void ssim_col_kernel(
    const float* __restrict__ pred, const float* __restrict__ target,
    float* __restrict__ partial, G11 gw)
{
    const int tid = threadIdx.x;
    const int x   = blockIdx.x * 256 + tid;       // output column, 0..511
    const int y0  = blockIdx.y * CHUNK;           // first output row
    const int bc  = blockIdx.z;
    const float* pimg = pred   + (size_t)bc * (IMH * IMW);
    const float* timg = target + (size_t)bc * (IMH * IMW);

    // single per-lane byte offset of the leftmost tap (may be negative: OOB->0)
    const int vx = (x - 5) * 4;

    // ring: hA = {h(p), h(t)}, hB = {h(p^2), h(t^2)}, hc = h(pt)
    f2    hA[KS], hB[KS];
    float hc[KS];
    #pragma unroll
    for (int i = 0; i < KS; ++i) { hA[i] = (f2){0.f, 0.f}; hB[i] = (f2){0.f, 0.f}; hc[i] = 0.f; }

    // named double prefetch buffers (static indexing only — rule #20)
    f2 pA[KS], pB[KS];

    // Issue the 22 loads of input row YI into BUF (no consumption here).
#define LOADROW(BUF, YI)                                                    \
    {                                                                       \
        const int yi = (YI);                                                \
        if ((unsigned)yi < (unsigned)IMH) {                                 \
            const v4i ps = make_row_srd(pimg + (size_t)yi * IMW);           \
            const v4i ts = make_row_srd(timg + (size_t)yi * IMW);           \
            _Pragma("unroll")                                               \
            for (int j = 0; j < KS; ++j) {                                  \
                BUF[j].x = raw_buf_load_f32(ps, vx + 4 * j, 0, 0);          \
                BUF[j].y = raw_buf_load_f32(ts, vx + 4 * j, 0, 0);          \
            }                                                               \
        }                                                                   \
    }

    // h-conv of BUF into ring slot S (S compile-time constant).
#define COMPUTE(BUF, S, YI)                                                 \
    {                                                                       \
        const int yi = (YI);                                                \
        f2 A = {0.f, 0.f}, Bq = {0.f, 0.f};                                 \
        float c4 = 0.f;                                                     \
        if ((unsigned)yi < (unsigned)IMH) {                                 \
            _Pragma("unroll")                                               \
            for (int j = 0; j < KS; ++j) {                                  \
                const f2 w2 = {gw.g[j], gw.g[j]};                           \
                const f2 wv = w2 * BUF[j];          /* {w p, w t} */        \
                A  = A + wv;                                                \
                Bq = __builtin_elementwise_fma(wv, BUF[j], Bq);             \
                c4 = fmaf(wv.x, BUF[j].y, c4);      /* w p t */             \
            }                                                               \
        }                                                                   \
        hA[S] = A; hB[S] = Bq; hc[S] = c4;                                  \
    }

    // Pipeline prologue: data for step 0 (input row y0-5) into pA.
    LOADROW(pA, y0 - 5)

    const float C1 = 1e-4f, C2 = 9e-4f;
    float acc = 0.f;

    // Step s (= 22*o + u) ingests input row y0-5+s into slot s%11 == u%11
    // and emits output row y = y0+s-10 (masked while the ring warms up and
    // past the image edge). Vertical tap j reads slot (s-10+j)%11 == (u+j+1)%11.
    for (int o = 0; o < 3; ++o) {
        const int s0 = 22 * o;
        #pragma unroll
        for (int u = 0; u < 22; ++u) {
            const int s = s0 + u;
            // issue next row's loads into the other buffer, then consume this row
            if ((u & 1) == 0) {
                LOADROW(pB, y0 - 5 + s + 1)
                COMPUTE(pA, u % KS, y0 - 5 + s)
            } else {
                LOADROW(pA, y0 - 5 + s + 1)
                COMPUTE(pB, u % KS, y0 - 5 + s)
            }

            f2 M = {0.f, 0.f}, S2 = {0.f, 0.f};
            float s12 = 0.f;
            #pragma unroll
            for (int j = 0; j < KS; ++j) {
                const f2 w2 = {gw.g[j], gw.g[j]};
                M   = __builtin_elementwise_fma(w2, hA[(u + j + 1) % KS], M);
                S2  = __builtin_elementwise_fma(w2, hB[(u + j + 1) % KS], S2);
                s12 = fmaf(gw.g[j], hc[(u + j + 1) % KS], s12);
            }
            const float m1 = M.x, m2 = M.y;
            const float mu1s = m1 * m1, mu2s = m2 * m2, mu12 = m1 * m2;
            const float sg1  = S2.x - mu1s;
            const float sg2  = S2.y - mu2s;
            const float sg12 = s12 - mu12;
            const float num = (2.f * mu12 + C1) * (2.f * sg12 + C2);
            const float den = (mu1s + mu2s + C1) * (sg1 + sg2 + C2);
            const float val = num * __builtin_amdgcn_rcpf(den);
            const int y = y0 + s - 10;
            acc += (s >= 10 && y < IMH) ? val : 0.f;
        }
    }
#undef LOADROW
#undef COMPUTE

    // Block reduction: wave shfl, then cross-wave via tiny LDS.
    __shared__ float wsum[4];
    #pragma unroll
    for (int off = 32; off > 0; off >>= 1) acc += __shfl_down(acc, off, 64);
    const int wid = tid >> 6, lane = tid & 63;
    if (lane == 0) wsum[wid] = acc;
    __syncthreads();
    if (tid == 0) {
        atomicAdd(partial, wsum[0] + wsum[1] + wsum[2] + wsum[3]);
    }
}

__global__ void ssim_final_kernel(const float* __restrict__ partial,
                                  float* __restrict__ out, float invN)
{
    out[0] = 1.f - partial[0] * invN;
}

extern "C" void kernel_launch(void* const* d_in, const int* in_sizes, int n_in,
                              void* d_out, int out_size, void* d_ws, size_t ws_size,
                              hipStream_t stream) {
    const float* pred   = (const float*)d_in[0];
    const float* target = (const float*)d_in[1];
    float* out = (float*)d_out;
    float* partial = (float*)d_ws;

    const int B = 16, C = 3;
    const float invN = 1.0f / ((float)B * C * IMH * IMW);

    // separable 1-D Gaussian, same formula as reference (sigma=1.5, 11 taps)
    G11 gw;
    {
        float s = 0.f;
        for (int i = 0; i < KS; ++i) {
            double e = exp(-((double)((i - 5) * (i - 5))) / (2.0 * 1.5 * 1.5));
            gw.g[i] = (float)e;
            s += gw.g[i];
        }
        for (int i = 0; i < KS; ++i) gw.g[i] /= s;
    }

    hipMemsetAsync(partial, 0, sizeof(float), stream);

    dim3 grid(IMW / 256, GRIDY, B * C);   // 2 x 10 x 48 = 960 blocks
    dim3 block(256);
    ssim_col_kernel<<<grid, block, 0, stream>>>(pred, target, partial, gw);
    ssim_final_kernel<<<1, 1, 0, stream>>>(partial, out, invN);
}

// Round 10
// 93.635 us; speedup vs baseline: 2.1052x; 2.1052x over previous
//
#include <hip/hip_runtime.h>
#include <math.h>

#define KS 11
#define CHUNK 55      // output rows per block = 5 x 11 (ring phases static)
#define GRIDY 10      // 10*55 = 550 >= 512; tail rows masked out of the sum
#define IMW 512
#define IMH 512

struct G11 { float g[KS]; };

typedef int   v4i __attribute__((ext_vector_type(4)));
typedef float f2  __attribute__((ext_vector_type(2)));
typedef float f4  __attribute__((ext_vector_type(4)));

// CK-style direct bindings to the raw buffer load intrinsics: compiler
// tracks the loads (auto waitcnt) and folds the +16/+32/+40 into the
// 12-bit imm offset, so all 8 loads share ONE voffset register.
__device__ float raw_buf_load_f32(v4i srsrc, int voffset, int soffset, int aux)
    __asm("llvm.amdgcn.raw.buffer.load.f32");
__device__ f2    raw_buf_load_v2 (v4i srsrc, int voffset, int soffset, int aux)
    __asm("llvm.amdgcn.raw.buffer.load.v2f32");
__device__ f4    raw_buf_load_v4 (v4i srsrc, int voffset, int soffset, int aux)
    __asm("llvm.amdgcn.raw.buffer.load.v4f32");

// SRD over ONE image row: num_records = IMW*4 bytes, stride 0.
// MUBUF bounds-checking is per-dword, so edge dwords of a dwordx4
// individually return 0 — exactly the reference conv's zero-padding.
__device__ inline v4i make_row_srd(const float* row) {
    union { const float* p; unsigned u[2]; } a; a.p = row;
    v4i r;
    r.x = (int)a.u[0];
    r.y = (int)a.u[1];
    r.z = IMW * 4;          // num_records (bytes, stride==0)
    r.w = 0x00020000;       // raw untyped dword access
    return r;
}

__device__ inline f2 ffma2(f2 a, f2 b, f2 c) {
    return __builtin_elementwise_fma(a, b, c);
}

// Each thread owns one output column x and streams CHUNK rows downward.
// Horizontal conv runs as packed-f32 pair-sums directly on the natural
// dwordx4/dwordx2 load destinations (aligned VGPR pairs, no pairing movs).
// Ring: hA = {h(p),h(t)}, hB = {h(p^2),h(t^2)}, hc = h(pt); every ring
// index is a compile-time constant (phase trick, CHUNK % 11 == 0).
__global__ __launch_bounds__(256, 1) void ssim_col_kernel(
    const float* __restrict__ pred, const float* __restrict__ target,
    float* __restrict__ partial, G11 gw)
{
    const int tid = threadIdx.x;
    const int x   = blockIdx.x * 256 + tid;       // output column, 0..511
    const int y0  = blockIdx.y * CHUNK;           // first output row
    const int bc  = blockIdx.z;
    const float* pimg = pred   + (size_t)bc * (IMH * IMW);
    const float* timg = target + (size_t)bc * (IMH * IMW);

    // single per-lane byte offset of the leftmost tap (may be negative: OOB->0)
    const int vx = (x - 5) * 4;

    // weight pairs (SGPR pairs for VOP3P) + last tap
    const f2 w01 = {gw.g[0], gw.g[1]};
    const f2 w23 = {gw.g[2], gw.g[3]};
    const f2 w45 = {gw.g[4], gw.g[5]};
    const f2 w67 = {gw.g[6], gw.g[7]};
    const f2 w89 = {gw.g[8], gw.g[9]};
    const float g10 = gw.g[10];

    f2    hA[KS], hB[KS];
    float hc[KS];

    // Ingest input row YI into ring slot S (S compile-time constant).
#define INGEST(S, YI)                                                       \
    {                                                                       \
        const int yi = (YI);                                                \
        float a0 = 0.f, a1 = 0.f, a2 = 0.f, a3 = 0.f, a4 = 0.f;             \
        if ((unsigned)yi < (unsigned)IMH) {                                 \
            const v4i ps = make_row_srd(pimg + (size_t)yi * IMW);           \
            const v4i ts = make_row_srd(timg + (size_t)yi * IMW);           \
            const f4 Pa = raw_buf_load_v4(ps, vx,      0, 0);               \
            const f4 Pb = raw_buf_load_v4(ps, vx + 16, 0, 0);               \
            const f2 Pc = raw_buf_load_v2(ps, vx + 32, 0, 0);               \
            const float pd = raw_buf_load_f32(ps, vx + 40, 0, 0);           \
            const f4 Ta = raw_buf_load_v4(ts, vx,      0, 0);               \
            const f4 Tb = raw_buf_load_v4(ts, vx + 16, 0, 0);               \
            const f2 Tc = raw_buf_load_v2(ts, vx + 32, 0, 0);               \
            const float td = raw_buf_load_f32(ts, vx + 40, 0, 0);           \
            const f2 PaL = __builtin_shufflevector(Pa, Pa, 0, 1);           \
            const f2 PaH = __builtin_shufflevector(Pa, Pa, 2, 3);           \
            const f2 PbL = __builtin_shufflevector(Pb, Pb, 0, 1);           \
            const f2 PbH = __builtin_shufflevector(Pb, Pb, 2, 3);           \
            const f2 TaL = __builtin_shufflevector(Ta, Ta, 0, 1);           \
            const f2 TaH = __builtin_shufflevector(Ta, Ta, 2, 3);           \
            const f2 TbL = __builtin_shufflevector(Tb, Tb, 0, 1);           \
            const f2 TbH = __builtin_shufflevector(Tb, Tb, 2, 3);           \
            /* shared w*p, w*t pair products */                             \
            const f2 wpA = w01 * PaL, wpB = w23 * PaH;                      \
            const f2 wpC = w45 * PbL, wpD = w67 * PbH;                      \
            const f2 wpE = w89 * Pc;                                        \
            const float wp10 = g10 * pd;                                    \
            const f2 wtA = w01 * TaL, wtB = w23 * TaH;                      \
            const f2 wtC = w45 * TbL, wtD = w67 * TbH;                      \
            const f2 wtE = w89 * Tc;                                        \
            const float wt10 = g10 * td;                                    \
            /* h(p), h(t) */                                                \
            const f2 v0 = (wpA + wpB) + (wpC + wpD) + wpE;                  \
            const f2 v1 = (wtA + wtB) + (wtC + wtD) + wtE;                  \
            a0 = v0.x + v0.y + wp10;                                        \
            a1 = v1.x + v1.y + wt10;                                        \
            /* h(p^2), h(t^2) */                                            \
            const f2 v2 = ffma2(wpA, PaL, ffma2(wpB, PaH,                   \
                           ffma2(wpC, PbL, ffma2(wpD, PbH, wpE * Pc))));    \
            a2 = fmaf(wp10, pd, v2.x + v2.y);                               \
            const f2 v3 = ffma2(wtA, TaL, ffma2(wtB, TaH,                   \
                           ffma2(wtC, TbL, ffma2(wtD, TbH, wtE * Tc))));    \
            a3 = fmaf(wt10, td, v3.x + v3.y);                               \
            /* h(p*t) */                                                    \
            const f2 v4 = ffma2(wpA, TaL, ffma2(wpB, TaH,                   \
                           ffma2(wpC, TbL, ffma2(wpD, TbH, wpE * Tc))));    \
            a4 = fmaf(wp10, td, v4.x + v4.y);                               \
        }                                                                   \
        hA[S] = (f2){a0, a1}; hB[S] = (f2){a2, a3}; hc[S] = a4;             \
    }

    // Prologue: fill slots 0..9 with input rows y0-5 .. y0+4.
    #pragma unroll
    for (int i = 0; i < 10; ++i) {
        INGEST(i, y0 - 5 + i)
    }

    const float C1 = 1e-4f, C2 = 9e-4f;
    float acc = 0.f;

    // Main: output row y = y0+k0+kk; ingest input row y+5 into slot
    // (kk+10)%11; vertical tap j reads slot (kk+j)%11. k0 is a multiple
    // of 11, so all slots depend only on kk (compile-time).
    for (int k0 = 0; k0 < CHUNK; k0 += KS) {
        #pragma unroll
        for (int kk = 0; kk < KS; ++kk) {
            const int k = k0 + kk;
            INGEST((kk + 10) % KS, y0 + k + 5)

            f2 M = {0.f, 0.f}, S2 = {0.f, 0.f};
            float s12 = 0.f;
            #pragma unroll
            for (int j = 0; j < KS; ++j) {
                const f2 w2 = {gw.g[j], gw.g[j]};
                M   = ffma2(w2, hA[(kk + j) % KS], M);
                S2  = ffma2(w2, hB[(kk + j) % KS], S2);
                s12 = fmaf(gw.g[j], hc[(kk + j) % KS], s12);
            }
            const float m1 = M.x, m2 = M.y;
            const float mu1s = m1 * m1, mu2s = m2 * m2, mu12 = m1 * m2;
            const float sg1  = S2.x - mu1s;
            const float sg2  = S2.y - mu2s;
            const float sg12 = s12 - mu12;
            const float num = (2.f * mu12 + C1) * (2.f * sg12 + C2);
            const float den = (mu1s + mu2s + C1) * (sg1 + sg2 + C2);
            const float val = num * __builtin_amdgcn_rcpf(den);
            // mask output rows beyond the image (block y=9 covers 495..549)
            acc += (y0 + k < IMH) ? val : 0.f;
        }
    }
#undef INGEST

    // Block reduction: wave shfl, then cross-wave via tiny LDS.
    __shared__ float wsum[4];
    #pragma unroll
    for (int off = 32; off > 0; off >>= 1) acc += __shfl_down(acc, off, 64);
    const int wid = tid >> 6, lane = tid & 63;
    if (lane == 0) wsum[wid] = acc;
    __syncthreads();
    if (tid == 0) {
        atomicAdd(partial, wsum[0] + wsum[1] + wsum[2] + wsum[3]);
    }
}

__global__ void ssim_final_kernel(const float* __restrict__ partial,
                                  float* __restrict__ out, float invN)
{
    out[0] = 1.f - partial[0] * invN;
}

extern "C" void kernel_launch(void* const* d_in, const int* in_sizes, int n_in,
                              void* d_out, int out_size, void* d_ws, size_t ws_size,
                              hipStream_t stream) {
    const float* pred   = (const float*)d_in[0];
    const float* target = (const float*)d_in[1];
    float* out = (float*)d_out;
    float* partial = (float*)d_ws;

    const int B = 16, C = 3;
    const float invN = 1.0f / ((float)B * C * IMH * IMW);

    // separable 1-D Gaussian, same formula as reference (sigma=1.5, 11 taps)
    G11 gw;
    {
        float s = 0.f;
        for (int i = 0; i < KS; ++i) {
            double e = exp(-((double)((i - 5) * (i - 5))) / (2.0 * 1.5 * 1.5));
            gw.g[i] = (float)e;
            s += gw.g[i];
        }
        for (int i = 0; i < KS; ++i) gw.g[i] /= s;
    }

    hipMemsetAsync(partial, 0, sizeof(float), stream);

    dim3 grid(IMW / 256, GRIDY, B * C);   // 2 x 10 x 48 = 960 blocks
    dim3 block(256);
    ssim_col_kernel<<<grid, block, 0, stream>>>(pred, target, partial, gw);
    ssim_final_kernel<<<1, 1, 0, stream>>>(partial, out, invN);
}

// Round 11
// 93.026 us; speedup vs baseline: 2.1190x; 1.0065x over previous
//
#include <hip/hip_runtime.h>
#include <math.h>

#define KS 11
#define CHUNK 33      // output rows per block = 3 x 11 (ring phases static)
#define GRIDY 16      // 16*33 = 528 >= 512; tail rows masked out of the sum
#define IMW 512
#define IMH 512

struct G11 { float g[KS]; };

typedef int   v4i __attribute__((ext_vector_type(4)));
typedef float f2  __attribute__((ext_vector_type(2)));
typedef float f4  __attribute__((ext_vector_type(4)));

// CK-style direct bindings to the raw buffer load intrinsics: compiler
// tracks the loads (auto waitcnt) and folds +16/+32/+40 into the 12-bit
// imm offset, so all 8 loads of a row share ONE voffset register.
__device__ float raw_buf_load_f32(v4i srsrc, int voffset, int soffset, int aux)
    __asm("llvm.amdgcn.raw.buffer.load.f32");
__device__ f2    raw_buf_load_v2 (v4i srsrc, int voffset, int soffset, int aux)
    __asm("llvm.amdgcn.raw.buffer.load.v2f32");
__device__ f4    raw_buf_load_v4 (v4i srsrc, int voffset, int soffset, int aux)
    __asm("llvm.amdgcn.raw.buffer.load.v4f32");

// SRD over ONE image row. nrec = IMW*4 for valid rows, 0 for out-of-image
// rows: every load then returns 0 (vertical zero-padding) with NO branch.
// Horizontal zero-padding comes from per-dword bounds checks (voffset<0
// wraps huge-unsigned -> OOB -> 0; voffset>=nrec -> 0).
__device__ inline v4i make_row_srd(const float* row, int nrec) {
    union { const float* p; unsigned u[2]; } a; a.p = row;
    v4i r;
    r.x = (int)a.u[0];
    r.y = (int)a.u[1];
    r.z = nrec;             // num_records (bytes, stride==0)
    r.w = 0x00020000;       // raw untyped dword access
    return r;
}

__device__ inline f2 ffma2(f2 a, f2 b, f2 c) {
    return __builtin_elementwise_fma(a, b, c);
}

// Each thread owns one output column x and streams CHUNK rows downward.
// Horizontal conv runs as packed-f32 pair-sums directly on the natural
// dwordx4/dwordx2 load destinations. INGEST is branchless (SRD-masked
// rows), so the compiler is free to pipeline loads across the unrolled
// 11-step body (loads of step s+1 overlap compute of step s).
__global__ __launch_bounds__(256, 1) void ssim_col_kernel(
    const float* __restrict__ pred, const float* __restrict__ target,
    float* __restrict__ partial, G11 gw)
{
    const int tid = threadIdx.x;
    const int x   = blockIdx.x * 256 + tid;       // output column, 0..511
    const int y0  = blockIdx.y * CHUNK;           // first output row
    const int bc  = blockIdx.z;
    const float* pimg = pred   + (size_t)bc * (IMH * IMW);
    const float* timg = target + (size_t)bc * (IMH * IMW);

    // single per-lane byte offset of the leftmost tap (may be negative: OOB->0)
    const int vx = (x - 5) * 4;

    // weight pairs (SGPR pairs for VOP3P) + last tap
    const f2 w01 = {gw.g[0], gw.g[1]};
    const f2 w23 = {gw.g[2], gw.g[3]};
    const f2 w45 = {gw.g[4], gw.g[5]};
    const f2 w67 = {gw.g[6], gw.g[7]};
    const f2 w89 = {gw.g[8], gw.g[9]};
    const float g10 = gw.g[10];

    f2    hA[KS], hB[KS];
    float hc[KS];

    // Ingest input row YI into ring slot S (S compile-time constant).
    // Branchless: invalid rows get num_records=0 -> all loads return 0.
#define INGEST(S, YI)                                                       \
    {                                                                       \
        const int yi = (YI);                                                \
        const int nrec = ((unsigned)yi < (unsigned)IMH) ? (IMW * 4) : 0;    \
        const int yc = yi < 0 ? 0 : (yi > IMH - 1 ? IMH - 1 : yi);          \
        const v4i ps = make_row_srd(pimg + (size_t)yc * IMW, nrec);         \
        const v4i ts = make_row_srd(timg + (size_t)yc * IMW, nrec);         \
        const f4 Pa = raw_buf_load_v4(ps, vx,      0, 0);                   \
        const f4 Pb = raw_buf_load_v4(ps, vx + 16, 0, 0);                   \
        const f2 Pc = raw_buf_load_v2(ps, vx + 32, 0, 0);                   \
        const float pd = raw_buf_load_f32(ps, vx + 40, 0, 0);               \
        const f4 Ta = raw_buf_load_v4(ts, vx,      0, 0);                   \
        const f4 Tb = raw_buf_load_v4(ts, vx + 16, 0, 0);                   \
        const f2 Tc = raw_buf_load_v2(ts, vx + 32, 0, 0);                   \
        const float td = raw_buf_load_f32(ts, vx + 40, 0, 0);               \
        const f2 PaL = __builtin_shufflevector(Pa, Pa, 0, 1);               \
        const f2 PaH = __builtin_shufflevector(Pa, Pa, 2, 3);               \
        const f2 PbL = __builtin_shufflevector(Pb, Pb, 0, 1);               \
        const f2 PbH = __builtin_shufflevector(Pb, Pb, 2, 3);               \
        const f2 TaL = __builtin_shufflevector(Ta, Ta, 0, 1);               \
        const f2 TaH = __builtin_shufflevector(Ta, Ta, 2, 3);               \
        const f2 TbL = __builtin_shufflevector(Tb, Tb, 0, 1);               \
        const f2 TbH = __builtin_shufflevector(Tb, Tb, 2, 3);               \
        /* shared w*p, w*t pair products */                                 \
        const f2 wpA = w01 * PaL, wpB = w23 * PaH;                          \
        const f2 wpC = w45 * PbL, wpD = w67 * PbH;                          \
        const f2 wpE = w89 * Pc;                                            \
        const float wp10 = g10 * pd;                                        \
        const f2 wtA = w01 * TaL, wtB = w23 * TaH;                          \
        const f2 wtC = w45 * TbL, wtD = w67 * TbH;                          \
        const f2 wtE = w89 * Tc;                                            \
        const float wt10 = g10 * td;                                        \
        /* h(p), h(t) */                                                    \
        const f2 v0 = (wpA + wpB) + (wpC + wpD) + wpE;                      \
        const f2 v1 = (wtA + wtB) + (wtC + wtD) + wtE;                      \
        /* h(p^2), h(t^2), h(pt) */                                         \
        const f2 v2 = ffma2(wpA, PaL, ffma2(wpB, PaH,                       \
                       ffma2(wpC, PbL, ffma2(wpD, PbH, wpE * Pc))));        \
        const f2 v3 = ffma2(wtA, TaL, ffma2(wtB, TaH,                       \
                       ffma2(wtC, TbL, ffma2(wtD, TbH, wtE * Tc))));        \
        const f2 v4 = ffma2(wpA, TaL, ffma2(wpB, TaH,                       \
                       ffma2(wpC, TbL, ffma2(wpD, TbH, wpE * Tc))));        \
        hA[S] = (f2){v0.x + v0.y + wp10, v1.x + v1.y + wt10};               \
        hB[S] = (f2){fmaf(wp10, pd, v2.x + v2.y),                           \
                     fmaf(wt10, td, v3.x + v3.y)};                          \
        hc[S] = fmaf(wp10, td, v4.x + v4.y);                                \
    }

    // Prologue: fill slots 0..9 with input rows y0-5 .. y0+4.
    #pragma unroll
    for (int i = 0; i < 10; ++i) {
        INGEST(i, y0 - 5 + i)
    }

    const float C1 = 1e-4f, C2 = 9e-4f;
    float acc = 0.f;

    // Main: output row y = y0+k0+kk; ingest input row y+5 into slot
    // (kk+10)%11; vertical tap j reads slot (kk+j)%11. k0 is a multiple
    // of 11, so all slots depend only on kk (compile-time).
    for (int k0 = 0; k0 < CHUNK; k0 += KS) {
        #pragma unroll
        for (int kk = 0; kk < KS; ++kk) {
            const int k = k0 + kk;
            INGEST((kk + 10) % KS, y0 + k + 5)

            f2 M = {0.f, 0.f}, S2 = {0.f, 0.f};
            float s12 = 0.f;
            #pragma unroll
            for (int j = 0; j < KS; ++j) {
                const f2 w2 = {gw.g[j], gw.g[j]};
                M   = ffma2(w2, hA[(kk + j) % KS], M);
                S2  = ffma2(w2, hB[(kk + j) % KS], S2);
                s12 = fmaf(gw.g[j], hc[(kk + j) % KS], s12);
            }
            const float m1 = M.x, m2 = M.y;
            const float mu1s = m1 * m1, mu2s = m2 * m2, mu12 = m1 * m2;
            const float sg1  = S2.x - mu1s;
            const float sg2  = S2.y - mu2s;
            const float sg12 = s12 - mu12;
            const float num = (2.f * mu12 + C1) * (2.f * sg12 + C2);
            const float den = (mu1s + mu2s + C1) * (sg1 + sg2 + C2);
            const float val = num * __builtin_amdgcn_rcpf(den);
            // mask output rows beyond the image (block y=15 covers 495..527)
            acc += (y0 + k < IMH) ? val : 0.f;
        }
    }
#undef INGEST

    // Block reduction: wave shfl, then cross-wave via tiny LDS.
    __shared__ float wsum[4];
    #pragma unroll
    for (int off = 32; off > 0; off >>= 1) acc += __shfl_down(acc, off, 64);
    const int wid = tid >> 6, lane = tid & 63;
    if (lane == 0) wsum[wid] = acc;
    __syncthreads();
    if (tid == 0) {
        atomicAdd(partial, wsum[0] + wsum[1] + wsum[2] + wsum[3]);
    }
}

__global__ void ssim_final_kernel(const float* __restrict__ partial,
                                  float* __restrict__ out, float invN)
{
    out[0] = 1.f - partial[0] * invN;
}

extern "C" void kernel_launch(void* const* d_in, const int* in_sizes, int n_in,
                              void* d_out, int out_size, void* d_ws, size_t ws_size,
                              hipStream_t stream) {
    const float* pred   = (const float*)d_in[0];
    const float* target = (const float*)d_in[1];
    float* out = (float*)d_out;
    float* partial = (float*)d_ws;

    const int B = 16, C = 3;
    const float invN = 1.0f / ((float)B * C * IMH * IMW);

    // separable 1-D Gaussian, same formula as reference (sigma=1.5, 11 taps)
    G11 gw;
    {
        float s = 0.f;
        for (int i = 0; i < KS; ++i) {
            double e = exp(-((double)((i - 5) * (i - 5))) / (2.0 * 1.5 * 1.5));
            gw.g[i] = (float)e;
            s += gw.g[i];
        }
        for (int i = 0; i < KS; ++i) gw.g[i] /= s;
    }

    hipMemsetAsync(partial, 0, sizeof(float), stream);

    dim3 grid(IMW / 256, GRIDY, B * C);   // 2 x 16 x 48 = 1536 blocks
    dim3 block(256);
    ssim_col_kernel<<<grid, block, 0, stream>>>(pred, target, partial, gw);
    ssim_final_kernel<<<1, 1, 0, stream>>>(partial, out, invN);
}

// Round 12
// 91.253 us; speedup vs baseline: 2.1601x; 1.0194x over previous
//
#include <hip/hip_runtime.h>
#include <math.h>

#define KS 11
#define CHUNK 44      // output rows per block = 4 x 11 (ring phases static)
#define GRIDY 12      // 12*44 = 528 >= 512; tail rows masked out of the sum
#define IMW 512
#define IMH 512

struct G11 { float g[KS]; };

typedef int   v4i __attribute__((ext_vector_type(4)));
typedef float f2  __attribute__((ext_vector_type(2)));
typedef float f4  __attribute__((ext_vector_type(4)));

// CK-style direct binding to the raw buffer load intrinsic: compiler tracks
// the loads (auto waitcnt) and folds +16/+32 into the 12-bit imm offset, so
// all 6 loads of a row share ONE voffset register.
__device__ f4 raw_buf_load_v4(v4i srsrc, int voffset, int soffset, int aux)
    __asm("llvm.amdgcn.raw.buffer.load.v4f32");

// SRD over ONE image row. nrec = IMW*4 for valid rows, 0 for out-of-image
// rows: every load then returns 0 (vertical zero-padding) with NO branch.
// Horizontal zero-padding comes from per-dword bounds checks (voffset<0
// wraps huge-unsigned -> OOB -> 0; voffset>=nrec -> 0).
__device__ inline v4i make_row_srd(const float* row, int nrec) {
    union { const float* p; unsigned u[2]; } a; a.p = row;
    v4i r;
    r.x = (int)a.u[0];
    r.y = (int)a.u[1];
    r.z = nrec;             // num_records (bytes, stride==0)
    r.w = 0x00020000;       // raw untyped dword access
    return r;
}

__device__ inline f2 ffma2(f2 a, f2 b, f2 c) {
    return __builtin_elementwise_fma(a, b, c);
}

// One staged input row: 12 floats per image starting at column x-6
// (element 0 carries weight 0; elements 1..11 are taps 0..10).
struct Row { f4 Pa, Pb, Pc, Ta, Tb, Tc; };

__device__ __forceinline__ Row load_row(const float* pimg, const float* timg,
                                        int yi, int vx2) {
    const int nrec = ((unsigned)yi < (unsigned)IMH) ? (IMW * 4) : 0;
    const int yc = yi < 0 ? 0 : (yi > IMH - 1 ? IMH - 1 : yi);
    const v4i ps = make_row_srd(pimg + (size_t)yc * IMW, nrec);
    const v4i ts = make_row_srd(timg + (size_t)yc * IMW, nrec);
    Row r;
    r.Pa = raw_buf_load_v4(ps, vx2,      0, 0);
    r.Pb = raw_buf_load_v4(ps, vx2 + 16, 0, 0);
    r.Pc = raw_buf_load_v4(ps, vx2 + 32, 0, 0);
    r.Ta = raw_buf_load_v4(ts, vx2,      0, 0);
    r.Tb = raw_buf_load_v4(ts, vx2 + 16, 0, 0);
    r.Tc = raw_buf_load_v4(ts, vx2 + 32, 0, 0);
    return r;
}

// Horizontal conv of a staged row -> 5 quantities, packed-f32 pair math
// on the natural dwordx4 halves (aligned VGPR pairs).
__device__ __forceinline__ void hconv(const Row& r,
                                      f2 W0, f2 W1, f2 W2, f2 W3, f2 W4, f2 W5,
                                      f2& oA, f2& oB, float& oC) {
    const f2 p0 = __builtin_shufflevector(r.Pa, r.Pa, 0, 1);
    const f2 p1 = __builtin_shufflevector(r.Pa, r.Pa, 2, 3);
    const f2 p2 = __builtin_shufflevector(r.Pb, r.Pb, 0, 1);
    const f2 p3 = __builtin_shufflevector(r.Pb, r.Pb, 2, 3);
    const f2 p4 = __builtin_shufflevector(r.Pc, r.Pc, 0, 1);
    const f2 p5 = __builtin_shufflevector(r.Pc, r.Pc, 2, 3);
    const f2 t0 = __builtin_shufflevector(r.Ta, r.Ta, 0, 1);
    const f2 t1 = __builtin_shufflevector(r.Ta, r.Ta, 2, 3);
    const f2 t2 = __builtin_shufflevector(r.Tb, r.Tb, 0, 1);
    const f2 t3 = __builtin_shufflevector(r.Tb, r.Tb, 2, 3);
    const f2 t4 = __builtin_shufflevector(r.Tc, r.Tc, 0, 1);
    const f2 t5 = __builtin_shufflevector(r.Tc, r.Tc, 2, 3);
    const f2 wp0 = W0 * p0, wp1 = W1 * p1, wp2 = W2 * p2;
    const f2 wp3 = W3 * p3, wp4 = W4 * p4, wp5 = W5 * p5;
    const f2 wt0 = W0 * t0, wt1 = W1 * t1, wt2 = W2 * t2;
    const f2 wt3 = W3 * t3, wt4 = W4 * t4, wt5 = W5 * t5;
    const f2 v0 = ((wp0 + wp1) + (wp2 + wp3)) + (wp4 + wp5);
    const f2 v1 = ((wt0 + wt1) + (wt2 + wt3)) + (wt4 + wt5);
    const f2 v2 = ffma2(wp0, p0, ffma2(wp1, p1, ffma2(wp2, p2,
                   ffma2(wp3, p3, ffma2(wp4, p4, wp5 * p5)))));
    const f2 v3 = ffma2(wt0, t0, ffma2(wt1, t1, ffma2(wt2, t2,
                   ffma2(wt3, t3, ffma2(wt4, t4, wt5 * t5)))));
    const f2 v4 = ffma2(wp0, t0, ffma2(wp1, t1, ffma2(wp2, t2,
                   ffma2(wp3, t3, ffma2(wp4, t4, wp5 * t5)))));
    oA = (f2){v0.x + v0.y, v1.x + v1.y};
    oB = (f2){v2.x + v2.y, v3.x + v3.y};
    oC = v4.x + v4.y;
}

// Each thread owns one output column x and streams CHUNK rows downward.
// Rotated pipeline: step k = { issue loads(row k+6) -> vertical+epilogue
// for output k (covers load latency in-wave) -> h-conv into ring slot }.
// Only one Row buffer is live across the vertical (+24 VGPR peak).
__global__ __launch_bounds__(256, 1) void ssim_col_kernel(
    const float* __restrict__ pred, const float* __restrict__ target,
    float* __restrict__ partial, G11 gw)
{
    const int tid = threadIdx.x;
    const int x   = blockIdx.x * 256 + tid;       // output column, 0..511
    const int y0  = blockIdx.y * CHUNK;           // first output row
    const int bc  = blockIdx.z;
    const float* pimg = pred   + (size_t)bc * (IMH * IMW);
    const float* timg = target + (size_t)bc * (IMH * IMW);

    // byte offset of column x-6 (element 0 of the 12-float window; may be
    // negative: unsigned-wrap -> OOB -> 0)
    const int vx2 = (x - 6) * 4;

    // weight pairs over the 12-float window (element 0 weight = 0)
    const f2 W0 = {0.f,      gw.g[0]};
    const f2 W1 = {gw.g[1],  gw.g[2]};
    const f2 W2 = {gw.g[3],  gw.g[4]};
    const f2 W3 = {gw.g[5],  gw.g[6]};
    const f2 W4 = {gw.g[7],  gw.g[8]};
    const f2 W5 = {gw.g[9],  gw.g[10]};

    // ring: hA = {h(p),h(t)}, hB = {h(p^2),h(t^2)}, hc = h(pt)
    // slot(row r) = (r - y0 + 5) % 11
    f2    hA[KS], hB[KS];
    float hc[KS];

    // Prologue: ingest input rows y0-5 .. y0+5 into slots 0..10.
    #pragma unroll
    for (int i = 0; i < KS; ++i) {
        Row r = load_row(pimg, timg, y0 - 5 + i, vx2);
        hconv(r, W0, W1, W2, W3, W4, W5, hA[i], hB[i], hc[i]);
    }

    const float C1 = 1e-4f, C2 = 9e-4f;
    float acc = 0.f;

    // Main: step k (output row y0+k). Ingested row k+6 lands in slot k%11
    // == kk; vertical tap j reads slot (k+j)%11 == (kk+j)%11 (k0 % 11 == 0,
    // all compile-time). Last step's ingest (row y0+CHUNK+5) is unused — 
    // accepted 1/55 waste to keep the body branchless.
    for (int k0 = 0; k0 < CHUNK; k0 += KS) {
        #pragma unroll
        for (int kk = 0; kk < KS; ++kk) {
            const int k = k0 + kk;

            // 1) issue next ingest row's loads (consumed only in step 3)
            Row r = load_row(pimg, timg, y0 + k + 6, vx2);

            // 2) vertical + SSIM for output row y0+k (ring is complete)
            f2 M = {0.f, 0.f}, S2 = {0.f, 0.f};
            float s12 = 0.f;
            #pragma unroll
            for (int j = 0; j < KS; ++j) {
                const f2 w2 = {gw.g[j], gw.g[j]};
                M   = ffma2(w2, hA[(kk + j) % KS], M);
                S2  = ffma2(w2, hB[(kk + j) % KS], S2);
                s12 = fmaf(gw.g[j], hc[(kk + j) % KS], s12);
            }
            const float m1 = M.x, m2 = M.y;
            const float mu1s = m1 * m1, mu2s = m2 * m2, mu12 = m1 * m2;
            const float sg1  = S2.x - mu1s;
            const float sg2  = S2.y - mu2s;
            const float sg12 = s12 - mu12;
            const float num = (2.f * mu12 + C1) * (2.f * sg12 + C2);
            const float den = (mu1s + mu2s + C1) * (sg1 + sg2 + C2);
            const float val = num * __builtin_amdgcn_rcpf(den);
            // mask output rows beyond the image (block y=11 covers 484..527)
            acc += (y0 + k < IMH) ? val : 0.f;

            // 3) h-conv the staged row into slot kk (WAR on ring keeps order)
            hconv(r, W0, W1, W2, W3, W4, W5, hA[kk], hB[kk], hc[kk]);
        }
    }

    // Block reduction: wave shfl, then cross-wave via tiny LDS.
    __shared__ float wsum[4];
    #pragma unroll
    for (int off = 32; off > 0; off >>= 1) acc += __shfl_down(acc, off, 64);
    const int wid = tid >> 6, lane = tid & 63;
    if (lane == 0) wsum[wid] = acc;
    __syncthreads();
    if (tid == 0) {
        atomicAdd(partial, wsum[0] + wsum[1] + wsum[2] + wsum[3]);
    }
}

__global__ void ssim_final_kernel(const float* __restrict__ partial,
                                  float* __restrict__ out, float invN)
{
    out[0] = 1.f - partial[0] * invN;
}

extern "C" void kernel_launch(void* const* d_in, const int* in_sizes, int n_in,
                              void* d_out, int out_size, void* d_ws, size_t ws_size,
                              hipStream_t stream) {
    const float* pred   = (const float*)d_in[0];
    const float* target = (const float*)d_in[1];
    float* out = (float*)d_out;
    float* partial = (float*)d_ws;

    const int B = 16, C = 3;
    const float invN = 1.0f / ((float)B * C * IMH * IMW);

    // separable 1-D Gaussian, same formula as reference (sigma=1.5, 11 taps)
    G11 gw;
    {
        float s = 0.f;
        for (int i = 0; i < KS; ++i) {
            double e = exp(-((double)((i - 5) * (i - 5))) / (2.0 * 1.5 * 1.5));
            gw.g[i] = (float)e;
            s += gw.g[i];
        }
        for (int i = 0; i < KS; ++i) gw.g[i] /= s;
    }

    hipMemsetAsync(partial, 0, sizeof(float), stream);

    dim3 grid(IMW / 256, GRIDY, B * C);   // 2 x 12 x 48 = 1152 blocks
    dim3 block(256);
    ssim_col_kernel<<<grid, block, 0, stream>>>(pred, target, partial, gw);
    ssim_final_kernel<<<1, 1, 0, stream>>>(partial, out, invN);
}